// Round 15
// baseline (106.816 us; speedup 1.0000x reference)
//
#include <hip/hip_runtime.h>

// Problem constants: B=4, C=64, H=W=64, N=4096
// Workspace layout (float offsets) — 4,747,264 floats (same proven footprint).
#define OFF_LP    0u          // lpart: 2 jh x 4 b x 4096 = 32768 floats
#define OFF_XV2   65536u
#define OFF_GP    589824u
#define OFF_Q2    1048576u
#define OFF_K2    2097152u
#define OFF_V2    3145728u    // V hi-only frags: 1,048,576 shorts
#define OFF_X2    3670016u    // bf16(x) Q-layout frags: 1,048,576 shorts
#define OFF_WT    4194304u    // W frags split-bf16: 221,184 shorts
#define OFF_A     4730880u    // A2 frags: 16,384 shorts
#define WS_FLOATS 4747264u

typedef short s8v __attribute__((ext_vector_type(8)));
typedef float f16v __attribute__((ext_vector_type(16)));

#define MFMA32(a, b, c) __builtin_amdgcn_mfma_f32_32x32x16_bf16((a), (b), (c), 0, 0, 0)

__device__ __forceinline__ unsigned short bf16_rne(float f) {
    union { float f; unsigned int u; } v; v.f = f;
    unsigned int r = v.u + 0x7FFFu + ((v.u >> 16) & 1u);
    return (unsigned short)(r >> 16);
}
__device__ __forceinline__ float bf2f(unsigned short h) {
    union { unsigned int u; float f; } t; t.u = ((unsigned int)h) << 16;
    return t.f;
}
__device__ __forceinline__ void split2(float f, unsigned short& h, unsigned short& l) {
    unsigned short hh = bf16_rne(f);
    h = hh;
    l = bf16_rne(f - bf2f(hh));
}
// packed f32x2 -> bf16x2 (RNE), lo in low half
__device__ __forceinline__ unsigned int cvtpk(float lo, float hi) {
    unsigned int r;
    asm("v_cvt_pk_bf16_f32 %0, %1, %2" : "=v"(r) : "v"(lo), "v"(hi));
    return r;
}
// v_permlane32_swap_b32: a.high32lanes <-> b.low32lanes (both regs updated)
__device__ __forceinline__ void pl32swap(unsigned int& a, unsigned int& b) {
    asm volatile("v_permlane32_swap_b32 %0, %1" : "+v"(a), "+v"(b));
}
__device__ __forceinline__ s8v mk8(unsigned int w0, unsigned int w1,
                                   unsigned int w2, unsigned int w3) {
    union { unsigned int u[4]; s8v v; } t;
    t.u[0] = w0; t.u[1] = w1; t.u[2] = w2; t.u[3] = w3;
    return t.v;
}
__device__ __forceinline__ f16v zero16() {
    f16v z;
#pragma unroll
    for (int i = 0; i < 16; ++i) z[i] = 0.0f;
    return z;
}

// Fragment layouts (32x32x16; mfma(A,B): D[lane&31]=B's lane, D[regs]=A's lane):
//  Q2/K2: idx = (((b*128 + nch)*4 + kst)*2 + hl)*512 + lane*8 + e
//  V2/XV2: idx = (((b*128 + ich)*2 + ksub)*2 + cb)*512 + lane*8 + e
//  X2:    Q2-pattern hi only; A2: ((b*2+cb)*4+kst)*512 + lane*8 + e

// ---------------- fused prep: W fragments (split-bf16) + x bf16 fragments
__global__ __launch_bounds__(256) void k_prep(
        const float* __restrict__ wq, const float* __restrict__ wk,
        const float* __restrict__ wv, const float* __restrict__ x,
        unsigned short* __restrict__ wf, unsigned short* __restrict__ X2,
        unsigned short* __restrict__ XV2) {
    int bid = blockIdx.x, tid = threadIdx.x;
    if (bid < 432) {
        int t = bid * 256 + tid;   // < 110592
        int f = t >> 9, pos = t & 511;
        int lane = pos >> 3, e = pos & 7;
        int oc = f & 1, kst = (f >> 1) & 3;
        int ct = f >> 3;
        int tap = ct % 9, conv = ct / 9;
        int o = oc * 32 + (lane & 31);
        int ci = kst * 16 + (lane >> 5) * 8 + e;
        const float* w = (conv == 0) ? wq : (conv == 1) ? wk : wv;
        float v = w[(o * 64 + ci) * 9 + tap];
        unsigned short hh, ll;
        split2(v, hh, ll);
        wf[(f * 2 + 0) * 512 + pos] = hh;
        wf[(f * 2 + 1) * 512 + pos] = ll;
    } else {
        int gid = (bid - 432) * 256 + tid;   // < 262144
        int b = gid >> 16;
        int c = (gid >> 10) & 63;
        int n4 = (gid & 1023) * 4;
        float4 v = *(const float4*)(x + (size_t)(b * 64 + c) * 4096 + n4);
        unsigned short hv[4] = {bf16_rne(v.x), bf16_rne(v.y), bf16_rne(v.z), bf16_rne(v.w)};
        int kst = c >> 4, e = c & 7, hb = (c >> 3) & 1;
#pragma unroll
        for (int u = 0; u < 4; ++u) {
            int n = n4 + u;
            int nch = n >> 5, lane = (n & 31) + 32 * hb;
            X2[(size_t)((b * 128 + nch) * 4 + kst) * 512 + lane * 8 + e] = hv[u];
        }
        int ich = n4 >> 5, ksub = (n4 >> 4) & 1, cb = c >> 5;
        int lane2 = (c & 31) + 32 * ((n4 >> 3) & 1);
        size_t xi = (size_t)(((b * 128 + ich) * 2 + ksub) * 2 + cb) * 512 + lane2 * 8 + (n4 & 7);
        unsigned long long w = (unsigned long long)hv[0]
                             | ((unsigned long long)hv[1] << 16)
                             | ((unsigned long long)hv[2] << 32)
                             | ((unsigned long long)hv[3] << 48);
        *(unsigned long long*)(XV2 + xi) = w;
    }
}

// ---------------- MFMA 3x3 conv (unchanged from r10)
__global__ __launch_bounds__(384) void k_conv(
        const float* __restrict__ x, const unsigned short* __restrict__ wf,
        const float* __restrict__ bq, const float* __restrict__ bk, const float* __restrict__ bv,
        unsigned short* __restrict__ Q2, unsigned short* __restrict__ K2,
        unsigned short* __restrict__ V2) {
    int nb = blockIdx.x;                 // 0..127 (n-block of 32)
    int b = blockIdx.y;
    int h = nb >> 1, w0 = (nb & 1) * 32;

    __shared__ unsigned short xwh[6528];  // [dy 3][W 34][c 64], XOR-swizzled
    __shared__ unsigned short xwl[6528];

    int tid = threadIdx.x;
    for (int idx = tid; idx < 6528; idx += 384) {
        int W = idx % 34;
        int c = (idx / 34) & 63;
        int dy = idx / (34 * 64);
        int hs = h + dy - 1, wi = w0 + W - 1;
        float v = 0.0f;
        if (hs >= 0 && hs < 64 && wi >= 0 && wi < 64)
            v = x[((b * 64 + c) * 64 + hs) * 64 + wi];
        unsigned short hh_, ll_;
        split2(v, hh_, ll_);
        int row = dy * 34 + W;
        int byt = row * 128 + c * 2;
        int swz = byt ^ ((row & 7) << 4);
        *(unsigned short*)((char*)xwh + swz) = hh_;
        *(unsigned short*)((char*)xwl + swz) = ll_;
    }
    __syncthreads();

    int lane = tid & 63, wv = tid >> 6;   // 6 waves
    int conv = wv >> 1, oc = wv & 1;
    int hh = lane >> 5, l31 = lane & 31;

    const float* bias = (conv == 0) ? bq : (conv == 1) ? bk : bv;
    f16v D;
    if (conv < 2) {
#pragma unroll
        for (int r = 0; r < 16; ++r)
            D[r] = bias[oc * 32 + (r & 3) + 8 * (r >> 2) + 4 * hh];
    } else {
        float bvv = bias[oc * 32 + l31];
#pragma unroll
        for (int r = 0; r < 16; ++r) D[r] = bvv;
    }

#pragma unroll
    for (int tap = 0; tap < 9; ++tap) {
        int dy = tap / 3, dx = tap % 3;
#pragma unroll
        for (int kst = 0; kst < 4; ++kst) {
            int f = ((conv * 9 + tap) * 4 + kst) * 2 + oc;
            s8v Wh = *(const s8v*)(wf + (f * 2 + 0) * 512 + lane * 8);
            s8v Wl = *(const s8v*)(wf + (f * 2 + 1) * 512 + lane * 8);
            int row = dy * 34 + dx + l31;
            int byt = row * 128 + kst * 32 + hh * 16;
            int swz = byt ^ ((row & 7) << 4);
            s8v Xh = *(const s8v*)((const char*)xwh + swz);
            s8v Xl = *(const s8v*)((const char*)xwl + swz);
            if (conv < 2) {
                D = MFMA32(Wh, Xh, D);
                D = MFMA32(Wh, Xl, D);
                D = MFMA32(Wl, Xh, D);
            } else {
                D = MFMA32(Xh, Wh, D);
                D = MFMA32(Xl, Wh, D);
                D = MFMA32(Xh, Wl, D);
            }
        }
    }

    if (conv < 2) {
        unsigned short sh[16], sl[16];
#pragma unroll
        for (int r = 0; r < 16; ++r) split2(D[r], sh[r], sl[r]);
        unsigned int ah0 = sh[0] | ((unsigned int)sh[1] << 16), ah1 = sh[2] | ((unsigned int)sh[3] << 16);
        unsigned int ah2 = sh[4] | ((unsigned int)sh[5] << 16), ah3 = sh[6] | ((unsigned int)sh[7] << 16);
        pl32swap(ah0, ah2); pl32swap(ah1, ah3);
        s8v F0h = mk8(ah0, ah1, ah2, ah3);
        unsigned int al0 = sl[0] | ((unsigned int)sl[1] << 16), al1 = sl[2] | ((unsigned int)sl[3] << 16);
        unsigned int al2 = sl[4] | ((unsigned int)sl[5] << 16), al3 = sl[6] | ((unsigned int)sl[7] << 16);
        pl32swap(al0, al2); pl32swap(al1, al3);
        s8v F0l = mk8(al0, al1, al2, al3);
        unsigned int bh0 = sh[8] | ((unsigned int)sh[9] << 16), bh1 = sh[10] | ((unsigned int)sh[11] << 16);
        unsigned int bh2 = sh[12] | ((unsigned int)sh[13] << 16), bh3 = sh[14] | ((unsigned int)sh[15] << 16);
        pl32swap(bh0, bh2); pl32swap(bh1, bh3);
        s8v F1h = mk8(bh0, bh1, bh2, bh3);
        unsigned int bl0 = sl[8] | ((unsigned int)sl[9] << 16), bl1 = sl[10] | ((unsigned int)sl[11] << 16);
        unsigned int bl2 = sl[12] | ((unsigned int)sl[13] << 16), bl3 = sl[14] | ((unsigned int)sl[15] << 16);
        pl32swap(bl0, bl2); pl32swap(bl1, bl3);
        s8v F1l = mk8(bl0, bl1, bl2, bl3);
        unsigned short* dst = (conv == 0) ? Q2 : K2;
        size_t b0 = (size_t)(((b * 128 + nb) * 4 + oc * 2 + 0) * 2) * 512 + lane * 8;
        size_t b1 = (size_t)(((b * 128 + nb) * 4 + oc * 2 + 1) * 2) * 512 + lane * 8;
        *(s8v*)(dst + b0) = F0h;
        *(s8v*)(dst + b0 + 512) = F0l;
        *(s8v*)(dst + b1) = F1h;
        *(s8v*)(dst + b1 + 512) = F1l;
    } else {
        unsigned int a0 = cvtpk(D[0], D[1]),  a1 = cvtpk(D[2], D[3]);
        unsigned int a2 = cvtpk(D[4], D[5]),  a3 = cvtpk(D[6], D[7]);
        pl32swap(a0, a2); pl32swap(a1, a3);
        s8v F0h = mk8(a0, a1, a2, a3);
        unsigned int b0w = cvtpk(D[8], D[9]),  b1w = cvtpk(D[10], D[11]);
        unsigned int b2w = cvtpk(D[12], D[13]), b3w = cvtpk(D[14], D[15]);
        pl32swap(b0w, b2w); pl32swap(b1w, b3w);
        s8v F1h = mk8(b0w, b1w, b2w, b3w);
        size_t v0 = (size_t)(((b * 128 + nb) * 2 + 0) * 2 + oc) * 512 + lane * 8;
        size_t v1 = (size_t)(((b * 128 + nb) * 2 + 1) * 2 + oc) * 512 + lane * 8;
        *(s8v*)(V2 + v0) = F0h;
        *(s8v*)(V2 + v1) = F1h;
    }
}

// ---------------- channel Gram via MFMA: grid (16 kp, 4 b), 4 waves = (cb1,cb2)
__global__ __launch_bounds__(256) void k_gram(const unsigned short* __restrict__ XV2,
                                              float* __restrict__ Gp) {
    int kp = blockIdx.x, b = blockIdx.y;
    int tid = threadIdx.x, lane = tid & 63, wv = tid >> 6;
    int cb1 = wv & 1, cb2 = wv >> 1;
    f16v G = zero16();
#pragma unroll
    for (int t = 0; t < 8; ++t) {
        int ich = kp * 8 + t;
        const unsigned short* base = XV2 + (size_t)(b * 128 + ich) * 2048 + lane * 8;
        s8v a0 = *(const s8v*)(base + (0 * 2 + cb1) * 512);
        s8v b0 = *(const s8v*)(base + (0 * 2 + cb2) * 512);
        s8v a1 = *(const s8v*)(base + (1 * 2 + cb1) * 512);
        s8v b1 = *(const s8v*)(base + (1 * 2 + cb2) * 512);
        G = MFMA32(a0, b0, G);
        G = MFMA32(a1, b1, G);
    }
    int hh = lane >> 5, l31 = lane & 31;
#pragma unroll
    for (int r = 0; r < 16; ++r) {
        int cc = cb1 * 32 + (r & 3) + 8 * (r >> 2) + 4 * hh;   // A's lane -> regs
        int dd = cb2 * 32 + l31;                               // B's lane -> lane
        Gp[(size_t)(kp * 4 + b) * 4096 + cc * 64 + dd] = G[r];
    }
}

// ---------------- channel softmax rows -> A2 bf16 fragments
__global__ void k_asm(const float* __restrict__ Gp, unsigned short* __restrict__ A2) {
    int row = blockIdx.x;      // b*64 + c
    int d = threadIdx.x;
    int b = row >> 6, c = row & 63;
    float g = 0.0f;
#pragma unroll
    for (int p = 0; p < 16; ++p) g += Gp[(size_t)(p * 4 + b) * 4096 + c * 64 + d];
    float mx = g;
    for (int off = 32; off >= 1; off >>= 1) mx = fmaxf(mx, __shfl_xor(mx, off, 64));
    float e = __expf(g - mx);
    float s = e;
    for (int off = 32; off >= 1; off >>= 1) s += __shfl_xor(s, off, 64);
    float a = e / s;
    int cb = c >> 5, kst = d >> 4;
    int lane2 = (c & 31) + 32 * ((d >> 3) & 1);
    A2[(size_t)((b * 2 + cb) * 4 + kst) * 512 + lane2 * 8 + (d & 7)] = bf16_rne(a);
}

// ---------------- pass1: ich-pair x j-half. grid 512; block 512.
// THIS ROUND: unroll 2 + relaxed launch_bounds (the lever that won on pass2).
__global__ __launch_bounds__(512) void k_pass1(
        const unsigned short* __restrict__ Q2, const unsigned short* __restrict__ K2,
        float* __restrict__ lpart) {
    int flat = blockIdx.x;                      // 0..511
    int xcd = flat & 7;
    int b = xcd >> 1;
    int rest = (xcd & 1) * 64 + (flat >> 3);    // 0..127
    int ichp = rest & 63, jh = rest >> 6;
    int ich0 = ichp * 2;
    int tid = threadIdx.x, lane = tid & 63, wv = tid >> 6;

    __shared__ float lsum[8][2][32];

    const unsigned short* qp = Q2 + (size_t)(b * 128 + ich0) * 4096 + lane * 8;
    s8v q0f0 = *(const s8v*)(qp);
    s8v q0f1 = *(const s8v*)(qp + 512);
    s8v q0f2 = *(const s8v*)(qp + 1024);
    s8v q0f3 = *(const s8v*)(qp + 1536);
    s8v q0f4 = *(const s8v*)(qp + 2048);
    s8v q0f5 = *(const s8v*)(qp + 2560);
    s8v q0f6 = *(const s8v*)(qp + 3072);
    s8v q0f7 = *(const s8v*)(qp + 3584);
    s8v q1f0 = *(const s8v*)(qp + 4096);
    s8v q1f1 = *(const s8v*)(qp + 4608);
    s8v q1f2 = *(const s8v*)(qp + 5120);
    s8v q1f3 = *(const s8v*)(qp + 5632);
    s8v q1f4 = *(const s8v*)(qp + 6144);
    s8v q1f5 = *(const s8v*)(qp + 6656);
    s8v q1f6 = *(const s8v*)(qp + 7168);
    s8v q1f7 = *(const s8v*)(qp + 7680);

    float la0 = 0.f, la1 = 0.f, lb0 = 0.f, lb1 = 0.f;
#pragma unroll 2
    for (int t = 0; t < 8; ++t) {
        int jch = jh * 64 + wv * 8 + t;
        const unsigned short* kp = K2 + (size_t)(b * 128 + jch) * 4096 + lane * 8;
        s8v kf0 = *(const s8v*)(kp);
        s8v kf1 = *(const s8v*)(kp + 512);
        s8v kf2 = *(const s8v*)(kp + 1024);
        s8v kf3 = *(const s8v*)(kp + 1536);
        s8v kf4 = *(const s8v*)(kp + 2048);
        s8v kf5 = *(const s8v*)(kp + 2560);
        s8v kf6 = *(const s8v*)(kp + 3072);
        s8v kf7 = *(const s8v*)(kp + 3584);
        {
            f16v Sa = zero16(), Sb = zero16();
            Sa = MFMA32(kf0, q0f0, Sa);
            Sa = MFMA32(kf0, q0f1, Sa);
            Sa = MFMA32(kf1, q0f0, Sa);
            Sa = MFMA32(kf2, q0f2, Sa);
            Sa = MFMA32(kf2, q0f3, Sa);
            Sa = MFMA32(kf3, q0f2, Sa);
            Sb = MFMA32(kf4, q0f4, Sb);
            Sb = MFMA32(kf4, q0f5, Sb);
            Sb = MFMA32(kf5, q0f4, Sb);
            Sb = MFMA32(kf6, q0f6, Sb);
            Sb = MFMA32(kf6, q0f7, Sb);
            Sb = MFMA32(kf7, q0f6, Sb);
#pragma unroll
            for (int r = 0; r < 8; ++r) la0 += __expf(Sa[r] + Sb[r]);
#pragma unroll
            for (int r = 8; r < 16; ++r) la1 += __expf(Sa[r] + Sb[r]);
        }
        {
            f16v Sa = zero16(), Sb = zero16();
            Sa = MFMA32(kf0, q1f0, Sa);
            Sa = MFMA32(kf0, q1f1, Sa);
            Sa = MFMA32(kf1, q1f0, Sa);
            Sa = MFMA32(kf2, q1f2, Sa);
            Sa = MFMA32(kf2, q1f3, Sa);
            Sa = MFMA32(kf3, q1f2, Sa);
            Sb = MFMA32(kf4, q1f4, Sb);
            Sb = MFMA32(kf4, q1f5, Sb);
            Sb = MFMA32(kf5, q1f4, Sb);
            Sb = MFMA32(kf6, q1f6, Sb);
            Sb = MFMA32(kf6, q1f7, Sb);
            Sb = MFMA32(kf7, q1f6, Sb);
#pragma unroll
            for (int r = 0; r < 8; ++r) lb0 += __expf(Sa[r] + Sb[r]);
#pragma unroll
            for (int r = 8; r < 16; ++r) lb1 += __expf(Sa[r] + Sb[r]);
        }
    }
    float lacc0 = la0 + la1;
    lacc0 += __shfl_xor(lacc0, 32);
    float lacc1 = lb0 + lb1;
    lacc1 += __shfl_xor(lacc1, 32);
    if (lane < 32) {
        lsum[wv][0][lane] = lacc0;
        lsum[wv][1][lane] = lacc1;
    }
    __syncthreads();
    if (tid < 64) {
        int ic = tid >> 5, iL = tid & 31;
        float s = 0.f;
#pragma unroll
        for (int p = 0; p < 8; ++p) s += lsum[p][ic][iL];
        lpart[jh * 16384 + b * 4096 + (ich0 + ic) * 32 + iL] = s;
    }
}

// ---------------- merge l-partials + fold 1/l into V (hi-only, in place)
__global__ __launch_bounds__(256) void k_mvn(
        unsigned short* __restrict__ V2, const float* __restrict__ lpart) {
    int u = blockIdx.x * 256 + threadIdx.x;      // < 131072 16B-segs
    int lane = u & 63, ksub = (u >> 7) & 1;
    int ich = (u >> 8) & 127, b = u >> 15;
    int n0 = ich * 32 + ksub * 16 + (lane >> 5) * 8;
    size_t base = (size_t)u * 8;
    s8v vh = *(s8v*)(V2 + base);
    const float* l0 = lpart + b * 4096 + n0;
    float4 a0 = *(const float4*)(l0);
    float4 a1 = *(const float4*)(l0 + 4);
    float4 c0 = *(const float4*)(l0 + 16384);
    float4 c1 = *(const float4*)(l0 + 16384 + 4);
    float lv[8] = {a0.x + c0.x, a0.y + c0.y, a0.z + c0.z, a0.w + c0.w,
                   a1.x + c1.x, a1.y + c1.y, a1.z + c1.z, a1.w + c1.w};
    s8v o;
#pragma unroll
    for (int e = 0; e < 8; ++e) {
        float inv = 1.0f / lv[e];
        o[e] = (short)bf16_rne(bf2f((unsigned short)vh[e]) * inv);
    }
    *(s8v*)(V2 + base) = o;
}

// ---------------- pass2 + fused final (r14 proven): jt-pair per block,
// grid 256, block 512, unroll 2.
__global__ __launch_bounds__(512) void k_pass2(
        const unsigned short* __restrict__ Q2, const unsigned short* __restrict__ K2,
        const unsigned short* __restrict__ V2, const unsigned short* __restrict__ X2,
        const unsigned short* __restrict__ A2, const float* __restrict__ x,
        const float* __restrict__ pg, const float* __restrict__ cg,
        float* __restrict__ out) {
    int flat = blockIdx.x;
    int xcd = flat & 7;
    int b = xcd >> 1;
    int jtp = (xcd & 1) * 32 + (flat >> 3);   // 0..63
    int jt0 = jtp * 2;
    int tid = threadIdx.x, lane = tid & 63, wv = tid >> 6;

    __shared__ float smem[12288];             // 48 KB
    unsigned short* Klds = (unsigned short*)(smem + 8192);   // 16 KB
    float* rl = smem;                         // [4][64][32] reduce buffer

    {
        const unsigned short* ksrc = K2 + (size_t)(b * 128 + jt0) * 4096;
#pragma unroll
        for (int s = 0; s < 2; ++s) {
            int seg = tid + s * 512;
            *(s8v*)(Klds + seg * 8) = *(const s8v*)(ksrc + seg * 8);
        }
    }
    __syncthreads();

    f16v O0a = zero16(), O1a = zero16();   // jt0: c-halves 0/1
    f16v O0b = zero16(), O1b = zero16();   // jt1

#pragma unroll 2
    for (int t = 0; t < 16; ++t) {
        int ich = wv * 16 + t;
        const unsigned short* qp = Q2 + (size_t)(b * 128 + ich) * 4096 + lane * 8;
        s8v qf0 = *(const s8v*)(qp);
        s8v qf1 = *(const s8v*)(qp + 512);
        s8v qf2 = *(const s8v*)(qp + 1024);
        s8v qf3 = *(const s8v*)(qp + 1536);
        s8v qf4 = *(const s8v*)(qp + 2048);
        s8v qf5 = *(const s8v*)(qp + 2560);
        s8v qf6 = *(const s8v*)(qp + 3072);
        s8v qf7 = *(const s8v*)(qp + 3584);
        const unsigned short* vp = V2 + (size_t)(b * 128 + ich) * 2048 + lane * 8;
        s8v vA = *(const s8v*)(vp);
        s8v vB = *(const s8v*)(vp + 512);
        s8v vC = *(const s8v*)(vp + 1024);
        s8v vD = *(const s8v*)(vp + 1536);

#pragma unroll
        for (int js = 0; js < 2; ++js) {
            const unsigned short* kl = Klds + js * 4096 + lane * 8;
            s8v kf0 = *(const s8v*)(kl);
            s8v kf1 = *(const s8v*)(kl + 512);
            s8v kf2 = *(const s8v*)(kl + 1024);
            s8v kf3 = *(const s8v*)(kl + 1536);
            s8v kf4 = *(const s8v*)(kl + 2048);
            s8v kf5 = *(const s8v*)(kl + 2560);
            s8v kf6 = *(const s8v*)(kl + 3072);
            s8v kf7 = *(const s8v*)(kl + 3584);

            f16v Sa = zero16(), Sb = zero16();
            Sa = MFMA32(qf0, kf0, Sa);
            Sa = MFMA32(qf0, kf1, Sa);
            Sa = MFMA32(qf1, kf0, Sa);
            Sa = MFMA32(qf2, kf2, Sa);
            Sa = MFMA32(qf2, kf3, Sa);
            Sa = MFMA32(qf3, kf2, Sa);
            Sb = MFMA32(qf4, kf4, Sb);
            Sb = MFMA32(qf4, kf5, Sb);
            Sb = MFMA32(qf5, kf4, Sb);
            Sb = MFMA32(qf6, kf6, Sb);
            Sb = MFMA32(qf6, kf7, Sb);
            Sb = MFMA32(qf7, kf6, Sb);

            float p[16];
#pragma unroll
            for (int r = 0; r < 16; ++r) p[r] = __expf(Sa[r] + Sb[r]);

            unsigned int a0 = cvtpk(p[0], p[1]),  a1 = cvtpk(p[2], p[3]);
            unsigned int a2 = cvtpk(p[4], p[5]),  a3 = cvtpk(p[6], p[7]);
            pl32swap(a0, a2);
            pl32swap(a1, a3);
            s8v P0 = mk8(a0, a1, a2, a3);
            unsigned int b0 = cvtpk(p[8], p[9]),  b1 = cvtpk(p[10], p[11]);
            unsigned int b2 = cvtpk(p[12], p[13]), b3 = cvtpk(p[14], p[15]);
            pl32swap(b0, b2);
            pl32swap(b1, b3);
            s8v P1 = mk8(b0, b1, b2, b3);

            if (js == 0) {
                O0a = MFMA32(vA, P0, O0a);
                O0a = MFMA32(vC, P1, O0a);
                O1a = MFMA32(vB, P0, O1a);
                O1a = MFMA32(vD, P1, O1a);
            } else {
                O0b = MFMA32(vA, P0, O0b);
                O0b = MFMA32(vC, P1, O0b);
                O1b = MFMA32(vB, P0, O1b);
                O1b = MFMA32(vD, P1, O1b);
            }
        }
    }

    int hh = lane >> 5, jj = lane & 31;
    float s0[4], s1[4];
    // ---- jt0 reduction (two rounds over i-parts)
    if (wv < 4) {
#pragma unroll
        for (int r = 0; r < 16; ++r) {
            int c = (r & 3) + 8 * (r >> 2) + 4 * hh;
            rl[(wv * 64 + c) * 32 + jj] = O0a[r];
            rl[(wv * 64 + c + 32) * 32 + jj] = O1a[r];
        }
    }
    __syncthreads();
#pragma unroll
    for (int k = 0; k < 4; ++k) {
        int el = tid + k * 512;
        s0[k] = ((rl[el] + rl[2048 + el]) + rl[4096 + el]) + rl[6144 + el];
    }
    __syncthreads();
    if (wv >= 4) {
#pragma unroll
        for (int r = 0; r < 16; ++r) {
            int c = (r & 3) + 8 * (r >> 2) + 4 * hh;
            rl[((wv - 4) * 64 + c) * 32 + jj] = O0a[r];
            rl[((wv - 4) * 64 + c + 32) * 32 + jj] = O1a[r];
        }
    }
    __syncthreads();
#pragma unroll
    for (int k = 0; k < 4; ++k) {
        int el = tid + k * 512;
        s0[k] = ((s0[k] + rl[el]) + rl[2048 + el]) + rl[4096 + el];
        s0[k] += rl[6144 + el];
    }
    __syncthreads();
    // ---- jt1 reduction
    if (wv < 4) {
#pragma unroll
        for (int r = 0; r < 16; ++r) {
            int c = (r & 3) + 8 * (r >> 2) + 4 * hh;
            rl[(wv * 64 + c) * 32 + jj] = O0b[r];
            rl[(wv * 64 + c + 32) * 32 + jj] = O1b[r];
        }
    }
    __syncthreads();
#pragma unroll
    for (int k = 0; k < 4; ++k) {
        int el = tid + k * 512;
        s1[k] = ((rl[el] + rl[2048 + el]) + rl[4096 + el]) + rl[6144 + el];
    }
    __syncthreads();
    if (wv >= 4) {
#pragma unroll
        for (int r = 0; r < 16; ++r) {
            int c = (r & 3) + 8 * (r >> 2) + 4 * hh;
            rl[((wv - 4) * 64 + c) * 32 + jj] = O0b[r];
            rl[((wv - 4) * 64 + c + 32) * 32 + jj] = O1b[r];
        }
    }
    __syncthreads();
#pragma unroll
    for (int k = 0; k < 4; ++k) {
        int el = tid + k * 512;
        s1[k] = ((s1[k] + rl[el]) + rl[2048 + el]) + rl[4096 + el];
        s1[k] += rl[6144 + el];
    }
    __syncthreads();                 // smem free for epilogue

    // ---- epilogue: chan apply (MFMA) + residual, for both jt
    float* chan = smem;              // [64][65] = 4160 floats
    float* xres = smem + 4160;       // [64][64] = 4096 floats
    if (wv < 4) {
        int jts = wv >> 1, cb = wv & 1;
        f16v Dc = zero16();
#pragma unroll
        for (int kst = 0; kst < 4; ++kst) {
            s8v af = *(const s8v*)(A2 + (size_t)((b * 2 + cb) * 4 + kst) * 512 + lane * 8);
            s8v xf = *(const s8v*)(X2 + (size_t)((b * 128 + jt0 + jts) * 4 + kst) * 512 + lane * 8);
            Dc = MFMA32(af, xf, Dc);
        }
#pragma unroll
        for (int r = 0; r < 16; ++r) {
            int c = cb * 32 + (r & 3) + 8 * (r >> 2) + 4 * hh;   // A's lane -> regs
            chan[c * 65 + jts * 32 + jj] = Dc[r];                // B's lane (n) -> lane
        }
    }
#pragma unroll
    for (int k = 0; k < 8; ++k) {
        int el = tid + k * 512;
        int c = el >> 6, j2 = el & 63;
        xres[el] = x[(size_t)(b * 64 + c) * 4096 + jtp * 64 + j2];
    }
    __syncthreads();
    float pgv = pg[0], cgv = cg[0];
#pragma unroll
    for (int k = 0; k < 4; ++k) {
        int el = tid + k * 512;
        int c = el >> 5, j2 = el & 31;
        size_t ob = (size_t)(b * 64 + c) * 4096 + jtp * 64;
        out[ob + j2] = pgv * s0[k] + cgv * chan[c * 65 + j2] + 2.0f * xres[c * 64 + j2];
        out[ob + 32 + j2] = pgv * s1[k] + cgv * chan[c * 65 + 32 + j2] + 2.0f * xres[c * 64 + 32 + j2];
    }
}

extern "C" void kernel_launch(void* const* d_in, const int* in_sizes, int n_in,
                              void* d_out, int out_size, void* d_ws, size_t ws_size,
                              hipStream_t stream) {
    const float* x  = (const float*)d_in[0];
    const float* wq = (const float*)d_in[1];
    const float* bq = (const float*)d_in[2];
    const float* wk = (const float*)d_in[3];
    const float* bk = (const float*)d_in[4];
    const float* wv = (const float*)d_in[5];
    const float* bv = (const float*)d_in[6];
    const float* pg = (const float*)d_in[7];
    const float* cg = (const float*)d_in[8];
    float* out = (float*)d_out;

    if (ws_size < (size_t)WS_FLOATS * sizeof(float)) return;
    float* ws = (float*)d_ws;
    float* lpart = ws + OFF_LP;
    unsigned short* XV2 = (unsigned short*)(ws + OFF_XV2);
    float* Gp = ws + OFF_GP;
    unsigned short* Q2  = (unsigned short*)(ws + OFF_Q2);
    unsigned short* K2  = (unsigned short*)(ws + OFF_K2);
    unsigned short* V2  = (unsigned short*)(ws + OFF_V2);
    unsigned short* X2  = (unsigned short*)(ws + OFF_X2);
    unsigned short* wfb = (unsigned short*)(ws + OFF_WT);
    unsigned short* A2  = (unsigned short*)(ws + OFF_A);

    k_prep<<<1456, 256, 0, stream>>>(wq, wk, wv, x, wfb, X2, XV2);
    k_conv<<<dim3(128, 4), 384, 0, stream>>>(x, wfb, bq, bk, bv, Q2, K2, V2);
    k_gram<<<dim3(16, 4), 256, 0, stream>>>(XV2, Gp);
    k_asm<<<256, 64, 0, stream>>>(Gp, A2);
    k_pass1<<<512, 512, 0, stream>>>(Q2, K2, lpart);
    k_mvn<<<512, 256, 0, stream>>>(V2, lpart);
    k_pass2<<<256, 512, 0, stream>>>(Q2, K2, V2, X2, A2, x, pg, cg, out);
}

// Round 16
// 105.062 us; speedup vs baseline: 1.0167x; 1.0167x over previous
//
#include <hip/hip_runtime.h>

// Problem constants: B=4, C=64, H=W=64, N=4096
// Workspace layout (float offsets) — 4,747,264 floats (same proven footprint).
#define OFF_LP    0u          // lpart: 2 jh x 4 b x 4096 = 32768 floats
#define OFF_XV2   65536u
#define OFF_GP    589824u
#define OFF_Q2    1048576u
#define OFF_K2    2097152u
#define OFF_V2    3145728u    // V hi-only frags: 1,048,576 shorts
#define OFF_X2    3670016u    // bf16(x) Q-layout frags: 1,048,576 shorts
#define OFF_WT    4194304u    // W frags split-bf16: 221,184 shorts
#define OFF_A     4730880u    // A2 frags: 16,384 shorts
#define WS_FLOATS 4747264u

typedef short s8v __attribute__((ext_vector_type(8)));
typedef float f16v __attribute__((ext_vector_type(16)));

#define MFMA32(a, b, c) __builtin_amdgcn_mfma_f32_32x32x16_bf16((a), (b), (c), 0, 0, 0)

__device__ __forceinline__ unsigned short bf16_rne(float f) {
    union { float f; unsigned int u; } v; v.f = f;
    unsigned int r = v.u + 0x7FFFu + ((v.u >> 16) & 1u);
    return (unsigned short)(r >> 16);
}
__device__ __forceinline__ float bf2f(unsigned short h) {
    union { unsigned int u; float f; } t; t.u = ((unsigned int)h) << 16;
    return t.f;
}
__device__ __forceinline__ void split2(float f, unsigned short& h, unsigned short& l) {
    unsigned short hh = bf16_rne(f);
    h = hh;
    l = bf16_rne(f - bf2f(hh));
}
// packed f32x2 -> bf16x2 (RNE), lo in low half
__device__ __forceinline__ unsigned int cvtpk(float lo, float hi) {
    unsigned int r;
    asm("v_cvt_pk_bf16_f32 %0, %1, %2" : "=v"(r) : "v"(lo), "v"(hi));
    return r;
}
// v_permlane32_swap_b32: a.high32lanes <-> b.low32lanes (both regs updated)
__device__ __forceinline__ void pl32swap(unsigned int& a, unsigned int& b) {
    asm volatile("v_permlane32_swap_b32 %0, %1" : "+v"(a), "+v"(b));
}
__device__ __forceinline__ s8v mk8(unsigned int w0, unsigned int w1,
                                   unsigned int w2, unsigned int w3) {
    union { unsigned int u[4]; s8v v; } t;
    t.u[0] = w0; t.u[1] = w1; t.u[2] = w2; t.u[3] = w3;
    return t.v;
}
__device__ __forceinline__ f16v zero16() {
    f16v z;
#pragma unroll
    for (int i = 0; i < 16; ++i) z[i] = 0.0f;
    return z;
}

// Fragment layouts (32x32x16; mfma(A,B): D[lane&31]=B's lane, D[regs]=A's lane):
//  Q2/K2: idx = (((b*128 + nch)*4 + kst)*2 + hl)*512 + lane*8 + e
//  V2/XV2: idx = (((b*128 + ich)*2 + ksub)*2 + cb)*512 + lane*8 + e
//  X2:    Q2-pattern hi only; A2: ((b*2+cb)*4+kst)*512 + lane*8 + e

// ---------------- fused prep: W fragments (split-bf16) + x bf16 fragments
__global__ __launch_bounds__(256) void k_prep(
        const float* __restrict__ wq, const float* __restrict__ wk,
        const float* __restrict__ wv, const float* __restrict__ x,
        unsigned short* __restrict__ wf, unsigned short* __restrict__ X2,
        unsigned short* __restrict__ XV2) {
    int bid = blockIdx.x, tid = threadIdx.x;
    if (bid < 432) {
        int t = bid * 256 + tid;   // < 110592
        int f = t >> 9, pos = t & 511;
        int lane = pos >> 3, e = pos & 7;
        int oc = f & 1, kst = (f >> 1) & 3;
        int ct = f >> 3;
        int tap = ct % 9, conv = ct / 9;
        int o = oc * 32 + (lane & 31);
        int ci = kst * 16 + (lane >> 5) * 8 + e;
        const float* w = (conv == 0) ? wq : (conv == 1) ? wk : wv;
        float v = w[(o * 64 + ci) * 9 + tap];
        unsigned short hh, ll;
        split2(v, hh, ll);
        wf[(f * 2 + 0) * 512 + pos] = hh;
        wf[(f * 2 + 1) * 512 + pos] = ll;
    } else {
        int gid = (bid - 432) * 256 + tid;   // < 262144
        int b = gid >> 16;
        int c = (gid >> 10) & 63;
        int n4 = (gid & 1023) * 4;
        float4 v = *(const float4*)(x + (size_t)(b * 64 + c) * 4096 + n4);
        unsigned short hv[4] = {bf16_rne(v.x), bf16_rne(v.y), bf16_rne(v.z), bf16_rne(v.w)};
        int kst = c >> 4, e = c & 7, hb = (c >> 3) & 1;
#pragma unroll
        for (int u = 0; u < 4; ++u) {
            int n = n4 + u;
            int nch = n >> 5, lane = (n & 31) + 32 * hb;
            X2[(size_t)((b * 128 + nch) * 4 + kst) * 512 + lane * 8 + e] = hv[u];
        }
        int ich = n4 >> 5, ksub = (n4 >> 4) & 1, cb = c >> 5;
        int lane2 = (c & 31) + 32 * ((n4 >> 3) & 1);
        size_t xi = (size_t)(((b * 128 + ich) * 2 + ksub) * 2 + cb) * 512 + lane2 * 8 + (n4 & 7);
        unsigned long long w = (unsigned long long)hv[0]
                             | ((unsigned long long)hv[1] << 16)
                             | ((unsigned long long)hv[2] << 32)
                             | ((unsigned long long)hv[3] << 48);
        *(unsigned long long*)(XV2 + xi) = w;
    }
}

// ---------------- MFMA 3x3 conv (unchanged from r10)
__global__ __launch_bounds__(384) void k_conv(
        const float* __restrict__ x, const unsigned short* __restrict__ wf,
        const float* __restrict__ bq, const float* __restrict__ bk, const float* __restrict__ bv,
        unsigned short* __restrict__ Q2, unsigned short* __restrict__ K2,
        unsigned short* __restrict__ V2) {
    int nb = blockIdx.x;                 // 0..127 (n-block of 32)
    int b = blockIdx.y;
    int h = nb >> 1, w0 = (nb & 1) * 32;

    __shared__ unsigned short xwh[6528];  // [dy 3][W 34][c 64], XOR-swizzled
    __shared__ unsigned short xwl[6528];

    int tid = threadIdx.x;
    for (int idx = tid; idx < 6528; idx += 384) {
        int W = idx % 34;
        int c = (idx / 34) & 63;
        int dy = idx / (34 * 64);
        int hs = h + dy - 1, wi = w0 + W - 1;
        float v = 0.0f;
        if (hs >= 0 && hs < 64 && wi >= 0 && wi < 64)
            v = x[((b * 64 + c) * 64 + hs) * 64 + wi];
        unsigned short hh_, ll_;
        split2(v, hh_, ll_);
        int row = dy * 34 + W;
        int byt = row * 128 + c * 2;
        int swz = byt ^ ((row & 7) << 4);
        *(unsigned short*)((char*)xwh + swz) = hh_;
        *(unsigned short*)((char*)xwl + swz) = ll_;
    }
    __syncthreads();

    int lane = tid & 63, wv = tid >> 6;   // 6 waves
    int conv = wv >> 1, oc = wv & 1;
    int hh = lane >> 5, l31 = lane & 31;

    const float* bias = (conv == 0) ? bq : (conv == 1) ? bk : bv;
    f16v D;
    if (conv < 2) {
#pragma unroll
        for (int r = 0; r < 16; ++r)
            D[r] = bias[oc * 32 + (r & 3) + 8 * (r >> 2) + 4 * hh];
    } else {
        float bvv = bias[oc * 32 + l31];
#pragma unroll
        for (int r = 0; r < 16; ++r) D[r] = bvv;
    }

#pragma unroll
    for (int tap = 0; tap < 9; ++tap) {
        int dy = tap / 3, dx = tap % 3;
#pragma unroll
        for (int kst = 0; kst < 4; ++kst) {
            int f = ((conv * 9 + tap) * 4 + kst) * 2 + oc;
            s8v Wh = *(const s8v*)(wf + (f * 2 + 0) * 512 + lane * 8);
            s8v Wl = *(const s8v*)(wf + (f * 2 + 1) * 512 + lane * 8);
            int row = dy * 34 + dx + l31;
            int byt = row * 128 + kst * 32 + hh * 16;
            int swz = byt ^ ((row & 7) << 4);
            s8v Xh = *(const s8v*)((const char*)xwh + swz);
            s8v Xl = *(const s8v*)((const char*)xwl + swz);
            if (conv < 2) {
                D = MFMA32(Wh, Xh, D);
                D = MFMA32(Wh, Xl, D);
                D = MFMA32(Wl, Xh, D);
            } else {
                D = MFMA32(Xh, Wh, D);
                D = MFMA32(Xl, Wh, D);
                D = MFMA32(Xh, Wl, D);
            }
        }
    }

    if (conv < 2) {
        unsigned short sh[16], sl[16];
#pragma unroll
        for (int r = 0; r < 16; ++r) split2(D[r], sh[r], sl[r]);
        unsigned int ah0 = sh[0] | ((unsigned int)sh[1] << 16), ah1 = sh[2] | ((unsigned int)sh[3] << 16);
        unsigned int ah2 = sh[4] | ((unsigned int)sh[5] << 16), ah3 = sh[6] | ((unsigned int)sh[7] << 16);
        pl32swap(ah0, ah2); pl32swap(ah1, ah3);
        s8v F0h = mk8(ah0, ah1, ah2, ah3);
        unsigned int al0 = sl[0] | ((unsigned int)sl[1] << 16), al1 = sl[2] | ((unsigned int)sl[3] << 16);
        unsigned int al2 = sl[4] | ((unsigned int)sl[5] << 16), al3 = sl[6] | ((unsigned int)sl[7] << 16);
        pl32swap(al0, al2); pl32swap(al1, al3);
        s8v F0l = mk8(al0, al1, al2, al3);
        unsigned int bh0 = sh[8] | ((unsigned int)sh[9] << 16), bh1 = sh[10] | ((unsigned int)sh[11] << 16);
        unsigned int bh2 = sh[12] | ((unsigned int)sh[13] << 16), bh3 = sh[14] | ((unsigned int)sh[15] << 16);
        pl32swap(bh0, bh2); pl32swap(bh1, bh3);
        s8v F1h = mk8(bh0, bh1, bh2, bh3);
        unsigned int bl0 = sl[8] | ((unsigned int)sl[9] << 16), bl1 = sl[10] | ((unsigned int)sl[11] << 16);
        unsigned int bl2 = sl[12] | ((unsigned int)sl[13] << 16), bl3 = sl[14] | ((unsigned int)sl[15] << 16);
        pl32swap(bl0, bl2); pl32swap(bl1, bl3);
        s8v F1l = mk8(bl0, bl1, bl2, bl3);
        unsigned short* dst = (conv == 0) ? Q2 : K2;
        size_t b0 = (size_t)(((b * 128 + nb) * 4 + oc * 2 + 0) * 2) * 512 + lane * 8;
        size_t b1 = (size_t)(((b * 128 + nb) * 4 + oc * 2 + 1) * 2) * 512 + lane * 8;
        *(s8v*)(dst + b0) = F0h;
        *(s8v*)(dst + b0 + 512) = F0l;
        *(s8v*)(dst + b1) = F1h;
        *(s8v*)(dst + b1 + 512) = F1l;
    } else {
        unsigned int a0 = cvtpk(D[0], D[1]),  a1 = cvtpk(D[2], D[3]);
        unsigned int a2 = cvtpk(D[4], D[5]),  a3 = cvtpk(D[6], D[7]);
        pl32swap(a0, a2); pl32swap(a1, a3);
        s8v F0h = mk8(a0, a1, a2, a3);
        unsigned int b0w = cvtpk(D[8], D[9]),  b1w = cvtpk(D[10], D[11]);
        unsigned int b2w = cvtpk(D[12], D[13]), b3w = cvtpk(D[14], D[15]);
        pl32swap(b0w, b2w); pl32swap(b1w, b3w);
        s8v F1h = mk8(b0w, b1w, b2w, b3w);
        size_t v0 = (size_t)(((b * 128 + nb) * 2 + 0) * 2 + oc) * 512 + lane * 8;
        size_t v1 = (size_t)(((b * 128 + nb) * 2 + 1) * 2 + oc) * 512 + lane * 8;
        *(s8v*)(V2 + v0) = F0h;
        *(s8v*)(V2 + v1) = F1h;
    }
}

// ---------------- channel Gram via MFMA: grid (16 kp, 4 b), 4 waves = (cb1,cb2)
__global__ __launch_bounds__(256) void k_gram(const unsigned short* __restrict__ XV2,
                                              float* __restrict__ Gp) {
    int kp = blockIdx.x, b = blockIdx.y;
    int tid = threadIdx.x, lane = tid & 63, wv = tid >> 6;
    int cb1 = wv & 1, cb2 = wv >> 1;
    f16v G = zero16();
#pragma unroll
    for (int t = 0; t < 8; ++t) {
        int ich = kp * 8 + t;
        const unsigned short* base = XV2 + (size_t)(b * 128 + ich) * 2048 + lane * 8;
        s8v a0 = *(const s8v*)(base + (0 * 2 + cb1) * 512);
        s8v b0 = *(const s8v*)(base + (0 * 2 + cb2) * 512);
        s8v a1 = *(const s8v*)(base + (1 * 2 + cb1) * 512);
        s8v b1 = *(const s8v*)(base + (1 * 2 + cb2) * 512);
        G = MFMA32(a0, b0, G);
        G = MFMA32(a1, b1, G);
    }
    int hh = lane >> 5, l31 = lane & 31;
#pragma unroll
    for (int r = 0; r < 16; ++r) {
        int cc = cb1 * 32 + (r & 3) + 8 * (r >> 2) + 4 * hh;   // A's lane -> regs
        int dd = cb2 * 32 + l31;                               // B's lane -> lane
        Gp[(size_t)(kp * 4 + b) * 4096 + cc * 64 + dd] = G[r];
    }
}

// ---------------- channel softmax rows -> A2 bf16 fragments
__global__ void k_asm(const float* __restrict__ Gp, unsigned short* __restrict__ A2) {
    int row = blockIdx.x;      // b*64 + c
    int d = threadIdx.x;
    int b = row >> 6, c = row & 63;
    float g = 0.0f;
#pragma unroll
    for (int p = 0; p < 16; ++p) g += Gp[(size_t)(p * 4 + b) * 4096 + c * 64 + d];
    float mx = g;
    for (int off = 32; off >= 1; off >>= 1) mx = fmaxf(mx, __shfl_xor(mx, off, 64));
    float e = __expf(g - mx);
    float s = e;
    for (int off = 32; off >= 1; off >>= 1) s += __shfl_xor(s, off, 64);
    float a = e / s;
    int cb = c >> 5, kst = d >> 4;
    int lane2 = (c & 31) + 32 * ((d >> 3) & 1);
    A2[(size_t)((b * 2 + cb) * 4 + kst) * 512 + lane2 * 8 + (d & 7)] = bf16_rne(a);
}

// ---------------- pass1: ich-QUAD x j-half (K stream reused 4x). grid 256
// (1 block/CU); block 512 (8 waves x 8 jch). Q: 32 frags in regs (128 VGPR).
__global__ __launch_bounds__(512) void k_pass1(
        const unsigned short* __restrict__ Q2, const unsigned short* __restrict__ K2,
        float* __restrict__ lpart) {
    int flat = blockIdx.x;                      // 0..255
    int xcd = flat & 7;
    int b = xcd >> 1;
    int rest = (xcd & 1) * 32 + (flat >> 3);    // 0..63
    int ichq = rest & 31, jh = rest >> 5;
    int ich0 = ichq * 4;
    int tid = threadIdx.x, lane = tid & 63, wv = tid >> 6;

    __shared__ float lsum[8][4][32];

    const unsigned short* qp = Q2 + (size_t)(b * 128 + ich0) * 4096 + lane * 8;
    s8v q0f0 = *(const s8v*)(qp);
    s8v q0f1 = *(const s8v*)(qp + 512);
    s8v q0f2 = *(const s8v*)(qp + 1024);
    s8v q0f3 = *(const s8v*)(qp + 1536);
    s8v q0f4 = *(const s8v*)(qp + 2048);
    s8v q0f5 = *(const s8v*)(qp + 2560);
    s8v q0f6 = *(const s8v*)(qp + 3072);
    s8v q0f7 = *(const s8v*)(qp + 3584);
    s8v q1f0 = *(const s8v*)(qp + 4096);
    s8v q1f1 = *(const s8v*)(qp + 4608);
    s8v q1f2 = *(const s8v*)(qp + 5120);
    s8v q1f3 = *(const s8v*)(qp + 5632);
    s8v q1f4 = *(const s8v*)(qp + 6144);
    s8v q1f5 = *(const s8v*)(qp + 6656);
    s8v q1f6 = *(const s8v*)(qp + 7168);
    s8v q1f7 = *(const s8v*)(qp + 7680);
    s8v q2f0 = *(const s8v*)(qp + 8192);
    s8v q2f1 = *(const s8v*)(qp + 8704);
    s8v q2f2 = *(const s8v*)(qp + 9216);
    s8v q2f3 = *(const s8v*)(qp + 9728);
    s8v q2f4 = *(const s8v*)(qp + 10240);
    s8v q2f5 = *(const s8v*)(qp + 10752);
    s8v q2f6 = *(const s8v*)(qp + 11264);
    s8v q2f7 = *(const s8v*)(qp + 11776);
    s8v q3f0 = *(const s8v*)(qp + 12288);
    s8v q3f1 = *(const s8v*)(qp + 12800);
    s8v q3f2 = *(const s8v*)(qp + 13312);
    s8v q3f3 = *(const s8v*)(qp + 13824);
    s8v q3f4 = *(const s8v*)(qp + 14336);
    s8v q3f5 = *(const s8v*)(qp + 14848);
    s8v q3f6 = *(const s8v*)(qp + 15360);
    s8v q3f7 = *(const s8v*)(qp + 15872);

    float l0a = 0.f, l0b = 0.f, l1a = 0.f, l1b = 0.f;
    float l2a = 0.f, l2b = 0.f, l3a = 0.f, l3b = 0.f;
#pragma unroll 1
    for (int t = 0; t < 8; ++t) {
        int jch = jh * 64 + wv * 8 + t;
        const unsigned short* kp = K2 + (size_t)(b * 128 + jch) * 4096 + lane * 8;
        s8v kf0 = *(const s8v*)(kp);
        s8v kf1 = *(const s8v*)(kp + 512);
        s8v kf2 = *(const s8v*)(kp + 1024);
        s8v kf3 = *(const s8v*)(kp + 1536);
        s8v kf4 = *(const s8v*)(kp + 2048);
        s8v kf5 = *(const s8v*)(kp + 2560);
        s8v kf6 = *(const s8v*)(kp + 3072);
        s8v kf7 = *(const s8v*)(kp + 3584);
        {
            f16v Sa = zero16(), Sb = zero16();
            Sa = MFMA32(kf0, q0f0, Sa);
            Sa = MFMA32(kf0, q0f1, Sa);
            Sa = MFMA32(kf1, q0f0, Sa);
            Sa = MFMA32(kf2, q0f2, Sa);
            Sa = MFMA32(kf2, q0f3, Sa);
            Sa = MFMA32(kf3, q0f2, Sa);
            Sb = MFMA32(kf4, q0f4, Sb);
            Sb = MFMA32(kf4, q0f5, Sb);
            Sb = MFMA32(kf5, q0f4, Sb);
            Sb = MFMA32(kf6, q0f6, Sb);
            Sb = MFMA32(kf6, q0f7, Sb);
            Sb = MFMA32(kf7, q0f6, Sb);
#pragma unroll
            for (int r = 0; r < 8; ++r) l0a += __expf(Sa[r] + Sb[r]);
#pragma unroll
            for (int r = 8; r < 16; ++r) l0b += __expf(Sa[r] + Sb[r]);
        }
        {
            f16v Sa = zero16(), Sb = zero16();
            Sa = MFMA32(kf0, q1f0, Sa);
            Sa = MFMA32(kf0, q1f1, Sa);
            Sa = MFMA32(kf1, q1f0, Sa);
            Sa = MFMA32(kf2, q1f2, Sa);
            Sa = MFMA32(kf2, q1f3, Sa);
            Sa = MFMA32(kf3, q1f2, Sa);
            Sb = MFMA32(kf4, q1f4, Sb);
            Sb = MFMA32(kf4, q1f5, Sb);
            Sb = MFMA32(kf5, q1f4, Sb);
            Sb = MFMA32(kf6, q1f6, Sb);
            Sb = MFMA32(kf6, q1f7, Sb);
            Sb = MFMA32(kf7, q1f6, Sb);
#pragma unroll
            for (int r = 0; r < 8; ++r) l1a += __expf(Sa[r] + Sb[r]);
#pragma unroll
            for (int r = 8; r < 16; ++r) l1b += __expf(Sa[r] + Sb[r]);
        }
        {
            f16v Sa = zero16(), Sb = zero16();
            Sa = MFMA32(kf0, q2f0, Sa);
            Sa = MFMA32(kf0, q2f1, Sa);
            Sa = MFMA32(kf1, q2f0, Sa);
            Sa = MFMA32(kf2, q2f2, Sa);
            Sa = MFMA32(kf2, q2f3, Sa);
            Sa = MFMA32(kf3, q2f2, Sa);
            Sb = MFMA32(kf4, q2f4, Sb);
            Sb = MFMA32(kf4, q2f5, Sb);
            Sb = MFMA32(kf5, q2f4, Sb);
            Sb = MFMA32(kf6, q2f6, Sb);
            Sb = MFMA32(kf6, q2f7, Sb);
            Sb = MFMA32(kf7, q2f6, Sb);
#pragma unroll
            for (int r = 0; r < 8; ++r) l2a += __expf(Sa[r] + Sb[r]);
#pragma unroll
            for (int r = 8; r < 16; ++r) l2b += __expf(Sa[r] + Sb[r]);
        }
        {
            f16v Sa = zero16(), Sb = zero16();
            Sa = MFMA32(kf0, q3f0, Sa);
            Sa = MFMA32(kf0, q3f1, Sa);
            Sa = MFMA32(kf1, q3f0, Sa);
            Sa = MFMA32(kf2, q3f2, Sa);
            Sa = MFMA32(kf2, q3f3, Sa);
            Sa = MFMA32(kf3, q3f2, Sa);
            Sb = MFMA32(kf4, q3f4, Sb);
            Sb = MFMA32(kf4, q3f5, Sb);
            Sb = MFMA32(kf5, q3f4, Sb);
            Sb = MFMA32(kf6, q3f6, Sb);
            Sb = MFMA32(kf6, q3f7, Sb);
            Sb = MFMA32(kf7, q3f6, Sb);
#pragma unroll
            for (int r = 0; r < 8; ++r) l3a += __expf(Sa[r] + Sb[r]);
#pragma unroll
            for (int r = 8; r < 16; ++r) l3b += __expf(Sa[r] + Sb[r]);
        }
    }
    float s0 = l0a + l0b;  s0 += __shfl_xor(s0, 32);
    float s1 = l1a + l1b;  s1 += __shfl_xor(s1, 32);
    float s2 = l2a + l2b;  s2 += __shfl_xor(s2, 32);
    float s3 = l3a + l3b;  s3 += __shfl_xor(s3, 32);
    if (lane < 32) {
        lsum[wv][0][lane] = s0;
        lsum[wv][1][lane] = s1;
        lsum[wv][2][lane] = s2;
        lsum[wv][3][lane] = s3;
    }
    __syncthreads();
    if (tid < 128) {
        int ic = tid >> 5, iL = tid & 31;
        float s = 0.f;
#pragma unroll
        for (int p = 0; p < 8; ++p) s += lsum[p][ic][iL];
        lpart[jh * 16384 + b * 4096 + (ich0 + ic) * 32 + iL] = s;
    }
}

// ---------------- merge l-partials + fold 1/l into V (hi-only, in place)
__global__ __launch_bounds__(256) void k_mvn(
        unsigned short* __restrict__ V2, const float* __restrict__ lpart) {
    int u = blockIdx.x * 256 + threadIdx.x;      // < 131072 16B-segs
    int lane = u & 63, ksub = (u >> 7) & 1;
    int ich = (u >> 8) & 127, b = u >> 15;
    int n0 = ich * 32 + ksub * 16 + (lane >> 5) * 8;
    size_t base = (size_t)u * 8;
    s8v vh = *(s8v*)(V2 + base);
    const float* l0 = lpart + b * 4096 + n0;
    float4 a0 = *(const float4*)(l0);
    float4 a1 = *(const float4*)(l0 + 4);
    float4 c0 = *(const float4*)(l0 + 16384);
    float4 c1 = *(const float4*)(l0 + 16384 + 4);
    float lv[8] = {a0.x + c0.x, a0.y + c0.y, a0.z + c0.z, a0.w + c0.w,
                   a1.x + c1.x, a1.y + c1.y, a1.z + c1.z, a1.w + c1.w};
    s8v o;
#pragma unroll
    for (int e = 0; e < 8; ++e) {
        float inv = 1.0f / lv[e];
        o[e] = (short)bf16_rne(bf2f((unsigned short)vh[e]) * inv);
    }
    *(s8v*)(V2 + base) = o;
}

// ---------------- pass2 + fused final (r14 proven): jt-pair per block,
// grid 256, block 512, unroll 2.
__global__ __launch_bounds__(512) void k_pass2(
        const unsigned short* __restrict__ Q2, const unsigned short* __restrict__ K2,
        const unsigned short* __restrict__ V2, const unsigned short* __restrict__ X2,
        const unsigned short* __restrict__ A2, const float* __restrict__ x,
        const float* __restrict__ pg, const float* __restrict__ cg,
        float* __restrict__ out) {
    int flat = blockIdx.x;
    int xcd = flat & 7;
    int b = xcd >> 1;
    int jtp = (xcd & 1) * 32 + (flat >> 3);   // 0..63
    int jt0 = jtp * 2;
    int tid = threadIdx.x, lane = tid & 63, wv = tid >> 6;

    __shared__ float smem[12288];             // 48 KB
    unsigned short* Klds = (unsigned short*)(smem + 8192);   // 16 KB
    float* rl = smem;                         // [4][64][32] reduce buffer

    {
        const unsigned short* ksrc = K2 + (size_t)(b * 128 + jt0) * 4096;
#pragma unroll
        for (int s = 0; s < 2; ++s) {
            int seg = tid + s * 512;
            *(s8v*)(Klds + seg * 8) = *(const s8v*)(ksrc + seg * 8);
        }
    }
    __syncthreads();

    f16v O0a = zero16(), O1a = zero16();   // jt0: c-halves 0/1
    f16v O0b = zero16(), O1b = zero16();   // jt1

#pragma unroll 2
    for (int t = 0; t < 16; ++t) {
        int ich = wv * 16 + t;
        const unsigned short* qp = Q2 + (size_t)(b * 128 + ich) * 4096 + lane * 8;
        s8v qf0 = *(const s8v*)(qp);
        s8v qf1 = *(const s8v*)(qp + 512);
        s8v qf2 = *(const s8v*)(qp + 1024);
        s8v qf3 = *(const s8v*)(qp + 1536);
        s8v qf4 = *(const s8v*)(qp + 2048);
        s8v qf5 = *(const s8v*)(qp + 2560);
        s8v qf6 = *(const s8v*)(qp + 3072);
        s8v qf7 = *(const s8v*)(qp + 3584);
        const unsigned short* vp = V2 + (size_t)(b * 128 + ich) * 2048 + lane * 8;
        s8v vA = *(const s8v*)(vp);
        s8v vB = *(const s8v*)(vp + 512);
        s8v vC = *(const s8v*)(vp + 1024);
        s8v vD = *(const s8v*)(vp + 1536);

#pragma unroll
        for (int js = 0; js < 2; ++js) {
            const unsigned short* kl = Klds + js * 4096 + lane * 8;
            s8v kf0 = *(const s8v*)(kl);
            s8v kf1 = *(const s8v*)(kl + 512);
            s8v kf2 = *(const s8v*)(kl + 1024);
            s8v kf3 = *(const s8v*)(kl + 1536);
            s8v kf4 = *(const s8v*)(kl + 2048);
            s8v kf5 = *(const s8v*)(kl + 2560);
            s8v kf6 = *(const s8v*)(kl + 3072);
            s8v kf7 = *(const s8v*)(kl + 3584);

            f16v Sa = zero16(), Sb = zero16();
            Sa = MFMA32(qf0, kf0, Sa);
            Sa = MFMA32(qf0, kf1, Sa);
            Sa = MFMA32(qf1, kf0, Sa);
            Sa = MFMA32(qf2, kf2, Sa);
            Sa = MFMA32(qf2, kf3, Sa);
            Sa = MFMA32(qf3, kf2, Sa);
            Sb = MFMA32(qf4, kf4, Sb);
            Sb = MFMA32(qf4, kf5, Sb);
            Sb = MFMA32(qf5, kf4, Sb);
            Sb = MFMA32(qf6, kf6, Sb);
            Sb = MFMA32(qf6, kf7, Sb);
            Sb = MFMA32(qf7, kf6, Sb);

            float p[16];
#pragma unroll
            for (int r = 0; r < 16; ++r) p[r] = __expf(Sa[r] + Sb[r]);

            unsigned int a0 = cvtpk(p[0], p[1]),  a1 = cvtpk(p[2], p[3]);
            unsigned int a2 = cvtpk(p[4], p[5]),  a3 = cvtpk(p[6], p[7]);
            pl32swap(a0, a2);
            pl32swap(a1, a3);
            s8v P0 = mk8(a0, a1, a2, a3);
            unsigned int b0 = cvtpk(p[8], p[9]),  b1 = cvtpk(p[10], p[11]);
            unsigned int b2 = cvtpk(p[12], p[13]), b3 = cvtpk(p[14], p[15]);
            pl32swap(b0, b2);
            pl32swap(b1, b3);
            s8v P1 = mk8(b0, b1, b2, b3);

            if (js == 0) {
                O0a = MFMA32(vA, P0, O0a);
                O0a = MFMA32(vC, P1, O0a);
                O1a = MFMA32(vB, P0, O1a);
                O1a = MFMA32(vD, P1, O1a);
            } else {
                O0b = MFMA32(vA, P0, O0b);
                O0b = MFMA32(vC, P1, O0b);
                O1b = MFMA32(vB, P0, O1b);
                O1b = MFMA32(vD, P1, O1b);
            }
        }
    }

    int hh = lane >> 5, jj = lane & 31;
    float s0[4], s1[4];
    // ---- jt0 reduction (two rounds over i-parts)
    if (wv < 4) {
#pragma unroll
        for (int r = 0; r < 16; ++r) {
            int c = (r & 3) + 8 * (r >> 2) + 4 * hh;
            rl[(wv * 64 + c) * 32 + jj] = O0a[r];
            rl[(wv * 64 + c + 32) * 32 + jj] = O1a[r];
        }
    }
    __syncthreads();
#pragma unroll
    for (int k = 0; k < 4; ++k) {
        int el = tid + k * 512;
        s0[k] = ((rl[el] + rl[2048 + el]) + rl[4096 + el]) + rl[6144 + el];
    }
    __syncthreads();
    if (wv >= 4) {
#pragma unroll
        for (int r = 0; r < 16; ++r) {
            int c = (r & 3) + 8 * (r >> 2) + 4 * hh;
            rl[((wv - 4) * 64 + c) * 32 + jj] = O0a[r];
            rl[((wv - 4) * 64 + c + 32) * 32 + jj] = O1a[r];
        }
    }
    __syncthreads();
#pragma unroll
    for (int k = 0; k < 4; ++k) {
        int el = tid + k * 512;
        s0[k] = ((s0[k] + rl[el]) + rl[2048 + el]) + rl[4096 + el];
        s0[k] += rl[6144 + el];
    }
    __syncthreads();
    // ---- jt1 reduction
    if (wv < 4) {
#pragma unroll
        for (int r = 0; r < 16; ++r) {
            int c = (r & 3) + 8 * (r >> 2) + 4 * hh;
            rl[(wv * 64 + c) * 32 + jj] = O0b[r];
            rl[(wv * 64 + c + 32) * 32 + jj] = O1b[r];
        }
    }
    __syncthreads();
#pragma unroll
    for (int k = 0; k < 4; ++k) {
        int el = tid + k * 512;
        s1[k] = ((rl[el] + rl[2048 + el]) + rl[4096 + el]) + rl[6144 + el];
    }
    __syncthreads();
    if (wv >= 4) {
#pragma unroll
        for (int r = 0; r < 16; ++r) {
            int c = (r & 3) + 8 * (r >> 2) + 4 * hh;
            rl[((wv - 4) * 64 + c) * 32 + jj] = O0b[r];
            rl[((wv - 4) * 64 + c + 32) * 32 + jj] = O1b[r];
        }
    }
    __syncthreads();
#pragma unroll
    for (int k = 0; k < 4; ++k) {
        int el = tid + k * 512;
        s1[k] = ((s1[k] + rl[el]) + rl[2048 + el]) + rl[4096 + el];
        s1[k] += rl[6144 + el];
    }
    __syncthreads();                 // smem free for epilogue

    // ---- epilogue: chan apply (MFMA) + residual, for both jt
    float* chan = smem;              // [64][65] = 4160 floats
    float* xres = smem + 4160;       // [64][64] = 4096 floats
    if (wv < 4) {
        int jts = wv >> 1, cb = wv & 1;
        f16v Dc = zero16();
#pragma unroll
        for (int kst = 0; kst < 4; ++kst) {
            s8v af = *(const s8v*)(A2 + (size_t)((b * 2 + cb) * 4 + kst) * 512 + lane * 8);
            s8v xf = *(const s8v*)(X2 + (size_t)((b * 128 + jt0 + jts) * 4 + kst) * 512 + lane * 8);
            Dc = MFMA32(af, xf, Dc);
        }
#pragma unroll
        for (int r = 0; r < 16; ++r) {
            int c = cb * 32 + (r & 3) + 8 * (r >> 2) + 4 * hh;   // A's lane -> regs
            chan[c * 65 + jts * 32 + jj] = Dc[r];                // B's lane (n) -> lane
        }
    }
#pragma unroll
    for (int k = 0; k < 8; ++k) {
        int el = tid + k * 512;
        int c = el >> 6, j2 = el & 63;
        xres[el] = x[(size_t)(b * 64 + c) * 4096 + jtp * 64 + j2];
    }
    __syncthreads();
    float pgv = pg[0], cgv = cg[0];
#pragma unroll
    for (int k = 0; k < 4; ++k) {
        int el = tid + k * 512;
        int c = el >> 5, j2 = el & 31;
        size_t ob = (size_t)(b * 64 + c) * 4096 + jtp * 64;
        out[ob + j2] = pgv * s0[k] + cgv * chan[c * 65 + j2] + 2.0f * xres[c * 64 + j2];
        out[ob + 32 + j2] = pgv * s1[k] + cgv * chan[c * 65 + 32 + j2] + 2.0f * xres[c * 64 + 32 + j2];
    }
}

extern "C" void kernel_launch(void* const* d_in, const int* in_sizes, int n_in,
                              void* d_out, int out_size, void* d_ws, size_t ws_size,
                              hipStream_t stream) {
    const float* x  = (const float*)d_in[0];
    const float* wq = (const float*)d_in[1];
    const float* bq = (const float*)d_in[2];
    const float* wk = (const float*)d_in[3];
    const float* bk = (const float*)d_in[4];
    const float* wv = (const float*)d_in[5];
    const float* bv = (const float*)d_in[6];
    const float* pg = (const float*)d_in[7];
    const float* cg = (const float*)d_in[8];
    float* out = (float*)d_out;

    if (ws_size < (size_t)WS_FLOATS * sizeof(float)) return;
    float* ws = (float*)d_ws;
    float* lpart = ws + OFF_LP;
    unsigned short* XV2 = (unsigned short*)(ws + OFF_XV2);
    float* Gp = ws + OFF_GP;
    unsigned short* Q2  = (unsigned short*)(ws + OFF_Q2);
    unsigned short* K2  = (unsigned short*)(ws + OFF_K2);
    unsigned short* V2  = (unsigned short*)(ws + OFF_V2);
    unsigned short* X2  = (unsigned short*)(ws + OFF_X2);
    unsigned short* wfb = (unsigned short*)(ws + OFF_WT);
    unsigned short* A2  = (unsigned short*)(ws + OFF_A);

    k_prep<<<1456, 256, 0, stream>>>(wq, wk, wv, x, wfb, X2, XV2);
    k_conv<<<dim3(128, 4), 384, 0, stream>>>(x, wfb, bq, bk, bv, Q2, K2, V2);
    k_gram<<<dim3(16, 4), 256, 0, stream>>>(XV2, Gp);
    k_asm<<<256, 64, 0, stream>>>(Gp, A2);
    k_pass1<<<256, 512, 0, stream>>>(Q2, K2, lpart);
    k_mvn<<<512, 256, 0, stream>>>(V2, lpart);
    k_pass2<<<256, 512, 0, stream>>>(Q2, K2, V2, X2, A2, x, pg, cg, out);
}